// Round 5
// baseline (243.137 us; speedup 1.0000x reference)
//
#include <hip/hip_runtime.h>
#include <hip/hip_bf16.h>

#define NN 4096
#define DD 256
#define OO 256
#define ACH 8                 // adjacency n-rows per block; also bf16x8 K-chunk
#define NCH (NN / ACH)        // 512 adjacency chunks
#define YPT 4                 // y's per thread in K2
#define YSEG (256 * YPT)      // 1024 y's per K2 block

typedef __attribute__((ext_vector_type(4))) float f32x4;
typedef __attribute__((ext_vector_type(8))) short bf16x8;
typedef __attribute__((ext_vector_type(4))) unsigned int u32x4;

__device__ __forceinline__ short f2bfs(float f) {
    __hip_bfloat16 h = __float2bfloat16(f);
    short s;
    __builtin_memcpy(&s, &h, 2);
    return s;
}

// K1: XWT[o][m] = sum_k X[m][k] * W[k][o], bf16, layout [OO][NN]. m-tile 8, 512 blocks.
__global__ __launch_bounds__(256) void k1_xwt(
    const float* __restrict__ X, const float* __restrict__ W,
    unsigned short* __restrict__ XWT)
{
    __shared__ float xs[8][DD];
    const int t = threadIdx.x;
    const int m0 = blockIdx.x * 8;

    #pragma unroll
    for (int i = 0; i < 8; ++i)
        xs[i][t] = X[(size_t)(m0 + i) * DD + t];
    __syncthreads();

    float acc[8];
    #pragma unroll
    for (int m = 0; m < 8; ++m) acc[m] = 0.f;

    for (int k0 = 0; k0 < DD; k0 += 4) {
        float w0 = W[(size_t)(k0 + 0) * OO + t];
        float w1 = W[(size_t)(k0 + 1) * OO + t];
        float w2 = W[(size_t)(k0 + 2) * OO + t];
        float w3 = W[(size_t)(k0 + 3) * OO + t];
        #pragma unroll
        for (int m = 0; m < 8; ++m) {
            const f32x4 xv = *reinterpret_cast<const f32x4*>(&xs[m][k0]);
            acc[m] = fmaf(xv[0], w0, acc[m]);
            acc[m] = fmaf(xv[1], w1, acc[m]);
            acc[m] = fmaf(xv[2], w2, acc[m]);
            acc[m] = fmaf(xv[3], w3, acc[m]);
        }
    }

    unsigned int p[4];
    #pragma unroll
    for (int i = 0; i < 4; ++i) {
        unsigned lo = (unsigned short)f2bfs(acc[2 * i]);
        unsigned hi = (unsigned short)f2bfs(acc[2 * i + 1]);
        p[i] = lo | (hi << 16);
    }
    *reinterpret_cast<u32x4*>(XWT + (size_t)t * NN + m0) = (u32x4){p[0], p[1], p[2], p[3]};
}

// K2: pure streaming of adjacency + Beta. No LDS, no barriers, all dwordx4.
// Thread owns y0..y0+3 (12 accumulators). Per n: 1 beta x4 + 3 adj x4 loads.
// Also emits BetaTb[ch][y][8] bf16 (MFMA A-frag-ready transpose of Beta).
// grid (NCH=512, 4 y-segs) = 2048 blocks x 256 thr -> 8 blocks/CU, full occupancy.
__global__ __launch_bounds__(256) void k2_adj(
    const float* __restrict__ Adj, const float* __restrict__ Beta,
    float* __restrict__ apart,            // [NCH][NN][3] f32
    unsigned short* __restrict__ BetaTb)  // [NCH][NN][8] bf16
{
    const int t = threadIdx.x;
    const int ch = blockIdx.x;            // 0..511
    const int y0 = blockIdx.y * YSEG + t * YPT;
    const int nb = ch * ACH;

    const float* bp = Beta + (size_t)nb * NN + y0;
    const float* ap = Adj + ((size_t)nb * NN + y0) * 3;

    f32x4 br[ACH];
    float acc[YPT][3];
    #pragma unroll
    for (int i = 0; i < YPT; ++i)
        #pragma unroll
        for (int c = 0; c < 3; ++c) acc[i][c] = 0.f;

    #pragma unroll
    for (int i = 0; i < ACH; ++i) {
        br[i] = *reinterpret_cast<const f32x4*>(bp);
        const f32x4* av = reinterpret_cast<const f32x4*>(ap);
        const f32x4 a0 = __builtin_nontemporal_load(av + 0);
        const f32x4 a1 = __builtin_nontemporal_load(av + 1);
        const f32x4 a2 = __builtin_nontemporal_load(av + 2);
        const float b0 = br[i][0], b1 = br[i][1], b2 = br[i][2], b3 = br[i][3];
        acc[0][0] = fmaf(b0, a0[0], acc[0][0]);
        acc[0][1] = fmaf(b0, a0[1], acc[0][1]);
        acc[0][2] = fmaf(b0, a0[2], acc[0][2]);
        acc[1][0] = fmaf(b1, a0[3], acc[1][0]);
        acc[1][1] = fmaf(b1, a1[0], acc[1][1]);
        acc[1][2] = fmaf(b1, a1[1], acc[1][2]);
        acc[2][0] = fmaf(b2, a1[2], acc[2][0]);
        acc[2][1] = fmaf(b2, a1[3], acc[2][1]);
        acc[2][2] = fmaf(b2, a2[0], acc[2][2]);
        acc[3][0] = fmaf(b3, a2[1], acc[3][0]);
        acc[3][1] = fmaf(b3, a2[2], acc[3][1]);
        acc[3][2] = fmaf(b3, a2[3], acc[3][2]);
        bp += NN;
        ap += (size_t)NN * 3;
    }

    // adjacency partial: 12 contiguous floats at [ch][y0][0]
    float* op = apart + ((size_t)ch * NN + y0) * 3;
    f32x4* ov = reinterpret_cast<f32x4*>(op);
    ov[0] = (f32x4){acc[0][0], acc[0][1], acc[0][2], acc[1][0]};
    ov[1] = (f32x4){acc[1][1], acc[1][2], acc[2][0], acc[2][1]};
    ov[2] = (f32x4){acc[2][2], acc[3][0], acc[3][1], acc[3][2]};

    // BetaTb: for each owned y, 8 consecutive-n bf16 = one 16B store
    unsigned short* tp = BetaTb + ((size_t)ch * NN + y0) * ACH;
    #pragma unroll
    for (int yi = 0; yi < YPT; ++yi) {
        unsigned int p[4];
        #pragma unroll
        for (int j = 0; j < 4; ++j) {
            unsigned lo = (unsigned short)f2bfs(br[2 * j][yi]);
            unsigned hi = (unsigned short)f2bfs(br[2 * j + 1][yi]);
            p[j] = lo | (hi << 16);
        }
        *reinterpret_cast<u32x4*>(tp + (size_t)yi * ACH) = (u32x4){p[0], p[1], p[2], p[3]};
    }
}

// K2b: agg[y][c] = sum over 512 chunks of apart[ch][y][c]. 48 blocks x 256.
__global__ __launch_bounds__(256) void k2b_reduce(
    const float* __restrict__ apart, float* __restrict__ agg)
{
    const int idx = blockIdx.x * 256 + threadIdx.x;   // 0 .. NN*3-1
    float s = 0.f;
    for (int ch = 0; ch < NCH; ++ch)
        s += apart[(size_t)ch * NN * 3 + idx];
    agg[idx] = s;
}

// K4: gpart[sp][y][o] = sum_{n in split} Beta[n,y]*XW[n,o], all-bf16 dense loads.
// grid (64 y-blocks, nsplit), 256 thr = 4 waves; wave w: y-tile = bx*64+16w, o = all 256.
__global__ __launch_bounds__(256) void k4_gemm(
    const unsigned short* __restrict__ BetaTb, const unsigned short* __restrict__ XWT,
    float* __restrict__ gpart, int clen)
{
    const int t = threadIdx.x;
    const int lane = t & 63;
    const int w = t >> 6;
    const int g16 = lane >> 4, r16 = lane & 15;
    const int y0 = blockIdx.x * 64 + 16 * w;
    const int sp = blockIdx.y;
    const int nb = sp * clen;
    const int ksteps = clen / 32;

    f32x4 acc[16];
    #pragma unroll
    for (int f = 0; f < 16; ++f) acc[f] = (f32x4){0.f, 0.f, 0.f, 0.f};

    for (int kc = 0; kc < ksteps; ++kc) {
        const int n0 = nb + kc * 32;
        // A-frag: av[j] = Beta[n0+8*g16+j][y0+r16]  (one dense 16B load)
        const bf16x8 av = *reinterpret_cast<const bf16x8*>(
            BetaTb + ((size_t)(n0 / ACH + g16) * NN + y0 + r16) * ACH);
        const unsigned short* xp = XWT + (size_t)r16 * NN + n0 + 8 * g16;
        #pragma unroll
        for (int f = 0; f < 16; ++f) {
            const bf16x8 bv = *reinterpret_cast<const bf16x8*>(xp + (size_t)16 * f * NN);
            acc[f] = __builtin_amdgcn_mfma_f32_16x16x32_bf16(av, bv, acc[f], 0, 0, 0);
        }
    }

    float* gp = gpart + (size_t)sp * NN * OO;
    #pragma unroll
    for (int f = 0; f < 16; ++f) {
        const int o = 16 * f + r16;
        #pragma unroll
        for (int r = 0; r < 4; ++r)
            gp[(size_t)(y0 + 4 * g16 + r) * OO + o] = acc[f][r];
    }
}

// K3: out[y,o] = sum_sp gpart + agg[y]@Wa + bias
__global__ __launch_bounds__(256) void k3_final(
    const float* __restrict__ gpart, const float* __restrict__ agg,
    const float* __restrict__ W, const float* __restrict__ bias,
    float* __restrict__ Out, int nsplit)
{
    const int idx = blockIdx.x * 256 + threadIdx.x;   // 0 .. NN*OO/4-1
    const int y = idx >> 6;
    const int o = (idx & 63) * 4;

    f32x4 acc = {0.f, 0.f, 0.f, 0.f};
    for (int sp = 0; sp < nsplit; ++sp) {
        const f32x4 g = *reinterpret_cast<const f32x4*>(
            &gpart[(size_t)sp * NN * OO + (size_t)y * OO + o]);
        acc[0] += g[0]; acc[1] += g[1]; acc[2] += g[2]; acc[3] += g[3];
    }

    const float a0 = agg[y * 3 + 0], a1 = agg[y * 3 + 1], a2 = agg[y * 3 + 2];
    #pragma unroll
    for (int j = 0; j < 4; ++j) {
        const int oo = o + j;
        Out[(size_t)y * OO + oo] = acc[j]
            + a0 * W[(size_t)(DD + 0) * OO + oo]
            + a1 * W[(size_t)(DD + 1) * OO + oo]
            + a2 * W[(size_t)(DD + 2) * OO + oo]
            + bias[oo];
    }
}

extern "C" void kernel_launch(void* const* d_in, const int* in_sizes, int n_in,
                              void* d_out, int out_size, void* d_ws, size_t ws_size,
                              hipStream_t stream) {
    (void)in_sizes; (void)n_in; (void)out_size;
    const float* adj  = (const float*)d_in[0];  // (N, N, C)
    const float* X    = (const float*)d_in[1];  // (N, D)
    const float* Beta = (const float*)d_in[2];  // (N, N)
    const float* W    = (const float*)d_in[3];  // (D+C, O)
    const float* bias = (const float*)d_in[4];  // (O)
    float* out = (float*)d_out;                 // (N, O) fp32

    const size_t xwt_b   = (size_t)OO * NN * 2;              // 2 MB
    const size_t betat_b = (size_t)NN * NN * 2;              // 32 MB
    const size_t apart_b = (size_t)NCH * NN * 3 * 4;         // 24 MB
    const size_t agg_b   = (size_t)NN * 3 * 4;               // 48 KB

    int nsplit = 8;
    size_t gpart_b = (size_t)nsplit * NN * OO * 4;           // 32 MB
    if (ws_size < xwt_b + betat_b + apart_b + agg_b + gpart_b) {
        nsplit = 2;
        gpart_b = (size_t)nsplit * NN * OO * 4;
    }

    char* p = (char*)d_ws;
    unsigned short* XWT    = (unsigned short*)p;            p += xwt_b;
    unsigned short* BetaTb = (unsigned short*)p;            p += betat_b;
    float*          gpart  = (float*)p;                     p += gpart_b;
    float*          apart  = (float*)p;                     p += apart_b;
    float*          agg    = (float*)p;

    const int clen = NN / nsplit;

    k1_xwt<<<dim3(NN / 8), dim3(256), 0, stream>>>(X, W, XWT);
    k2_adj<<<dim3(NCH, NN / YSEG), dim3(256), 0, stream>>>(adj, Beta, apart, BetaTb);
    k2b_reduce<<<dim3(NN * 3 / 256), dim3(256), 0, stream>>>(apart, agg);
    k4_gemm<<<dim3(NN / 64, nsplit), dim3(256), 0, stream>>>(BetaTb, XWT, gpart, clen);
    k3_final<<<dim3(NN * OO / 4 / 256), dim3(256), 0, stream>>>(
        gpart, agg, W, bias, out, nsplit);
}

// Round 6
// 227.152 us; speedup vs baseline: 1.0704x; 1.0704x over previous
//
#include <hip/hip_runtime.h>
#include <hip/hip_bf16.h>

#define NN 4096
#define DD 256
#define OO 256
#define NR 8                  // adjacency rows per K2 block
#define ROWF (NN * 3)         // 12288 floats per adjacency row
#define NSPLIT 8

typedef __attribute__((ext_vector_type(4))) float f32x4;
typedef __attribute__((ext_vector_type(8))) short bf16x8;
typedef __attribute__((ext_vector_type(4))) unsigned int u32x4;

__device__ __forceinline__ short f2bfs(float f) {
    __hip_bfloat16 h = __float2bfloat16(f);
    short s;
    __builtin_memcpy(&s, &h, 2);
    return s;
}

// K1: XWT[o][m] = sum_k X[m][k] * W[k][o], bf16, layout [OO][NN]. 512 blocks.
__global__ __launch_bounds__(256) void k1_xwt(
    const float* __restrict__ X, const float* __restrict__ W,
    unsigned short* __restrict__ XWT)
{
    __shared__ float xs[8][DD];
    const int t = threadIdx.x;
    const int m0 = blockIdx.x * 8;

    #pragma unroll
    for (int i = 0; i < 8; ++i)
        xs[i][t] = X[(size_t)(m0 + i) * DD + t];
    __syncthreads();

    float acc[8];
    #pragma unroll
    for (int m = 0; m < 8; ++m) acc[m] = 0.f;

    for (int k0 = 0; k0 < DD; k0 += 4) {
        float w0 = W[(size_t)(k0 + 0) * OO + t];
        float w1 = W[(size_t)(k0 + 1) * OO + t];
        float w2 = W[(size_t)(k0 + 2) * OO + t];
        float w3 = W[(size_t)(k0 + 3) * OO + t];
        #pragma unroll
        for (int m = 0; m < 8; ++m) {
            const f32x4 xv = *reinterpret_cast<const f32x4*>(&xs[m][k0]);
            acc[m] = fmaf(xv[0], w0, acc[m]);
            acc[m] = fmaf(xv[1], w1, acc[m]);
            acc[m] = fmaf(xv[2], w2, acc[m]);
            acc[m] = fmaf(xv[3], w3, acc[m]);
        }
    }

    unsigned int p[4];
    #pragma unroll
    for (int i = 0; i < 4; ++i) {
        unsigned lo = (unsigned short)f2bfs(acc[2 * i]);
        unsigned hi = (unsigned short)f2bfs(acc[2 * i + 1]);
        p[i] = lo | (hi << 16);
    }
    *reinterpret_cast<u32x4*>(XWT + (size_t)t * NN + m0) = (u32x4){p[0], p[1], p[2], p[3]};
}

// K_T: BetaTb[ch][y][8] bf16 = Beta[ch*8+j][y]. Dense flat 128KB read, 64KB write per block.
// 512 blocks x 1024 threads.
__global__ __launch_bounds__(1024) void kt_transpose(
    const float* __restrict__ Beta, unsigned short* __restrict__ BetaTb)
{
    const int t = threadIdx.x;
    const int ch = blockIdx.x;
    const int n0 = ch * 8;

    f32x4 br[8];
    #pragma unroll
    for (int j = 0; j < 8; ++j)
        br[j] = *reinterpret_cast<const f32x4*>(Beta + (size_t)(n0 + j) * NN + t * 4);

    unsigned short* tp = BetaTb + ((size_t)ch * NN + t * 4) * 8;
    #pragma unroll
    for (int yi = 0; yi < 4; ++yi) {
        unsigned int p[4];
        #pragma unroll
        for (int j = 0; j < 4; ++j) {
            unsigned lo = (unsigned short)f2bfs(br[2 * j][yi]);
            unsigned hi = (unsigned short)f2bfs(br[2 * j + 1][yi]);
            p[j] = lo | (hi << 16);
        }
        *reinterpret_cast<u32x4*>(tp + (size_t)yi * 8) = (u32x4){p[0], p[1], p[2], p[3]};
    }
}

// K2: flat copy-shaped adjacency reduce. Block owns NR=8 rows = 384KB contiguous.
// Thread t owns 12 fixed (y,c) cells: flat offsets {p*4096 + 4t + q}. Register acc,
// prefetch-distance-1, no LDS/barriers in loop.
__global__ __launch_bounds__(1024, 8) void k2_stream(
    const float* __restrict__ Adj, const float* __restrict__ Beta,
    float* __restrict__ apart)
{
    __shared__ float red[ROWF];
    const int t = threadIdx.x;
    const int b = blockIdx.x;
    const int n0 = b * NR;

    int fpos[3], y0[3], rr[3];
    #pragma unroll
    for (int p = 0; p < 3; ++p) {
        fpos[p] = p * NN + t * 4;
        y0[p] = fpos[p] / 3;
        rr[p] = fpos[p] - 3 * y0[p];
    }

    const float* arow = Adj + (size_t)n0 * ROWF;
    const float* brow = Beta + (size_t)n0 * NN;

    f32x4 acc[3];
    #pragma unroll
    for (int p = 0; p < 3; ++p) acc[p] = (f32x4){0.f, 0.f, 0.f, 0.f};

    // prologue: row 0 in flight
    f32x4 pv[3];
    float pl[3], ph[3];
    #pragma unroll
    for (int p = 0; p < 3; ++p) {
        pv[p] = *reinterpret_cast<const f32x4*>(arow + fpos[p]);
        pl[p] = brow[y0[p]];
        ph[p] = brow[y0[p] + 1];
    }

    #pragma unroll
    for (int n = 0; n < NR; ++n) {
        f32x4 qv[3];
        float ql[3], qh[3];
        if (n + 1 < NR) {
            const float* an = arow + (size_t)(n + 1) * ROWF;
            const float* bn = brow + (size_t)(n + 1) * NN;
            #pragma unroll
            for (int p = 0; p < 3; ++p) {
                qv[p] = *reinterpret_cast<const f32x4*>(an + fpos[p]);
                ql[p] = bn[y0[p]];
                qh[p] = bn[y0[p] + 1];
            }
        }
        #pragma unroll
        for (int p = 0; p < 3; ++p) {
            #pragma unroll
            for (int q = 0; q < 4; ++q) {
                const float w = (rr[p] + q < 3) ? pl[p] : ph[p];
                acc[p][q] = fmaf(w, pv[p][q], acc[p][q]);
            }
        }
        if (n + 1 < NR) {
            #pragma unroll
            for (int p = 0; p < 3; ++p) {
                pv[p] = qv[p];
                pl[p] = ql[p];
                ph[p] = qh[p];
            }
        }
    }

    // scatter 12 cells into [y][c]-flat LDS, then fully dense write-out
    #pragma unroll
    for (int p = 0; p < 3; ++p)
        *reinterpret_cast<f32x4*>(&red[fpos[p]]) = acc[p];
    __syncthreads();

    float* op = apart + (size_t)b * ROWF;
    #pragma unroll
    for (int j = 0; j < 3; ++j) {
        const int i = t * 4 + j * NN;
        *reinterpret_cast<f32x4*>(op + i) = *reinterpret_cast<const f32x4*>(&red[i]);
    }
}

// K2b: agg[i] = sum over 512 blocks of apart[b][i]. 48 blocks x 256.
__global__ __launch_bounds__(256) void k2b_reduce(
    const float* __restrict__ apart, float* __restrict__ agg)
{
    const int idx = blockIdx.x * 256 + threadIdx.x;   // 0 .. ROWF-1
    float s = 0.f;
    for (int b = 0; b < NN / NR; ++b)
        s += apart[(size_t)b * ROWF + idx];
    agg[idx] = s;
}

// K4: gpart[sp][y][o] = sum_{n in split} Beta[n,y]*XW[n,o], all-bf16 dense loads.
// grid (64 y-blocks, NSPLIT), 256 thr = 4 waves.
__global__ __launch_bounds__(256) void k4_gemm(
    const unsigned short* __restrict__ BetaTb, const unsigned short* __restrict__ XWT,
    float* __restrict__ gpart, int clen)
{
    const int t = threadIdx.x;
    const int lane = t & 63;
    const int w = t >> 6;
    const int g16 = lane >> 4, r16 = lane & 15;
    const int y0 = blockIdx.x * 64 + 16 * w;
    const int sp = blockIdx.y;
    const int nb = sp * clen;
    const int ksteps = clen / 32;

    f32x4 acc[16];
    #pragma unroll
    for (int f = 0; f < 16; ++f) acc[f] = (f32x4){0.f, 0.f, 0.f, 0.f};

    for (int kc = 0; kc < ksteps; ++kc) {
        const int n0 = nb + kc * 32;
        const bf16x8 av = *reinterpret_cast<const bf16x8*>(
            BetaTb + ((size_t)(n0 / 8 + g16) * NN + y0 + r16) * 8);
        const unsigned short* xp = XWT + (size_t)r16 * NN + n0 + 8 * g16;
        #pragma unroll
        for (int f = 0; f < 16; ++f) {
            const bf16x8 bv = *reinterpret_cast<const bf16x8*>(xp + (size_t)16 * f * NN);
            acc[f] = __builtin_amdgcn_mfma_f32_16x16x32_bf16(av, bv, acc[f], 0, 0, 0);
        }
    }

    float* gp = gpart + (size_t)sp * NN * OO;
    #pragma unroll
    for (int f = 0; f < 16; ++f) {
        const int o = 16 * f + r16;
        #pragma unroll
        for (int r = 0; r < 4; ++r)
            gp[(size_t)(y0 + 4 * g16 + r) * OO + o] = acc[f][r];
    }
}

// K3: out[y,o] = sum_sp gpart + agg[y]@Wa + bias
__global__ __launch_bounds__(256) void k3_final(
    const float* __restrict__ gpart, const float* __restrict__ agg,
    const float* __restrict__ W, const float* __restrict__ bias,
    float* __restrict__ Out, int nsplit)
{
    const int idx = blockIdx.x * 256 + threadIdx.x;   // 0 .. NN*OO/4-1
    const int y = idx >> 6;
    const int o = (idx & 63) * 4;

    f32x4 acc = {0.f, 0.f, 0.f, 0.f};
    for (int sp = 0; sp < nsplit; ++sp) {
        const f32x4 g = *reinterpret_cast<const f32x4*>(
            &gpart[(size_t)sp * NN * OO + (size_t)y * OO + o]);
        acc[0] += g[0]; acc[1] += g[1]; acc[2] += g[2]; acc[3] += g[3];
    }

    const float a0 = agg[y * 3 + 0], a1 = agg[y * 3 + 1], a2 = agg[y * 3 + 2];
    #pragma unroll
    for (int j = 0; j < 4; ++j) {
        const int oo = o + j;
        Out[(size_t)y * OO + oo] = acc[j]
            + a0 * W[(size_t)(DD + 0) * OO + oo]
            + a1 * W[(size_t)(DD + 1) * OO + oo]
            + a2 * W[(size_t)(DD + 2) * OO + oo]
            + bias[oo];
    }
}

extern "C" void kernel_launch(void* const* d_in, const int* in_sizes, int n_in,
                              void* d_out, int out_size, void* d_ws, size_t ws_size,
                              hipStream_t stream) {
    (void)in_sizes; (void)n_in; (void)out_size;
    const float* adj  = (const float*)d_in[0];  // (N, N, C)
    const float* X    = (const float*)d_in[1];  // (N, D)
    const float* Beta = (const float*)d_in[2];  // (N, N)
    const float* W    = (const float*)d_in[3];  // (D+C, O)
    const float* bias = (const float*)d_in[4];  // (O)
    float* out = (float*)d_out;                 // (N, O) fp32

    const size_t xwt_b   = (size_t)OO * NN * 2;              // 2 MB
    const size_t betat_b = (size_t)NN * NN * 2;              // 32 MB
    const size_t apart_b = (size_t)(NN / NR) * ROWF * 4;     // 24 MB
    const size_t agg_b   = (size_t)ROWF * 4;                 // 48 KB

    int nsplit = NSPLIT;
    size_t gpart_b = (size_t)nsplit * NN * OO * 4;           // 32 MB
    if (ws_size < xwt_b + betat_b + apart_b + agg_b + gpart_b) {
        nsplit = 2;
        gpart_b = (size_t)nsplit * NN * OO * 4;
    }

    char* p = (char*)d_ws;
    unsigned short* XWT    = (unsigned short*)p;            p += xwt_b;
    unsigned short* BetaTb = (unsigned short*)p;            p += betat_b;
    float*          gpart  = (float*)p;                     p += gpart_b;
    float*          apart  = (float*)p;                     p += apart_b;
    float*          agg    = (float*)p;

    const int clen = NN / nsplit;

    k1_xwt<<<dim3(NN / 8), dim3(256), 0, stream>>>(X, W, XWT);
    kt_transpose<<<dim3(NN / 8), dim3(1024), 0, stream>>>(Beta, BetaTb);
    k2_stream<<<dim3(NN / NR), dim3(1024), 0, stream>>>(adj, Beta, apart);
    k2b_reduce<<<dim3(ROWF / 256), dim3(256), 0, stream>>>(apart, agg);
    k4_gemm<<<dim3(NN / 64, nsplit), dim3(256), 0, stream>>>(BetaTb, XWT, gpart, clen);
    k3_final<<<dim3(NN * OO / 4 / 256), dim3(256), 0, stream>>>(
        gpart, agg, W, bias, out, nsplit);
}